// Round 7
// baseline (567.363 us; speedup 1.0000x reference)
//
#include <hip/hip_runtime.h>
#include <math.h>

#define CH 256

typedef short short8 __attribute__((ext_vector_type(8)));
typedef float f32x4 __attribute__((ext_vector_type(4)));

// f32 -> bf16 bits (RNE); adjacency values are small ints, exact
__device__ inline ushort f2bf(float f) {
  unsigned u = __float_as_uint(f);
  unsigned r = (u + 0x7FFFu + ((u >> 16) & 1u)) >> 16;
  return (ushort)r;
}

// ---------------- build ----------------

__global__ void scatter_edges(const int* __restrict__ ei, int E, int n, float* __restrict__ A) {
  int e = blockIdx.x * blockDim.x + threadIdx.x;
  if (e < E) atomicAdd(&A[(size_t)ei[e] * n + ei[E + e]], 1.0f);
}

// ---------------- fused transpose + diag rule + column-degree ----------------
// DIAGMODE 0: diag v==0 -> 2.0 (GCN rule on raw A); DIAGMODE 1: diag forced 2.0 (post-augment)
template <int DIAGMODE>
__global__ __launch_bounds__(256) void transpose_deg(const float* __restrict__ In, int n,
                                                     ushort* __restrict__ O, float* __restrict__ deg) {
  __shared__ float t[64][65];
  int j0 = blockIdx.x * 64, i0 = blockIdx.y * 64;
  int tx = threadIdx.x & 63, ty4 = threadIdx.x >> 6;
  float s = 0.f;
#pragma unroll
  for (int r = 0; r < 64; r += 4) {
    int gi = i0 + ty4 + r, gj = j0 + tx;
    float v = In[(size_t)gi * n + gj];
    if (gi == gj) v = (DIAGMODE == 1) ? 2.0f : ((v != 0.f) ? v : 2.0f);
    t[ty4 + r][tx] = v;
    s += v;
  }
  atomicAdd(&deg[j0 + tx], s);
  __syncthreads();
#pragma unroll
  for (int r = 0; r < 64; r += 4) {
    int c = ty4 + r;
    O[(size_t)(j0 + c) * n + i0 + tx] = f2bf(t[tx][c]);
  }
}

// ---------------- top-k: bitonic sort on packed u64 (desc score, asc index) ----------------
__global__ __launch_bounds__(1024) void topk_sort(const float* __restrict__ sc, int n, int k,
                                                  int* __restrict__ perm, float* __restrict__ vals) {
  __shared__ unsigned long long key[4096];
  int tid = threadIdx.x;
  for (int i = tid; i < n; i += 1024) {
    unsigned u = __float_as_uint(sc[i]);
    u = (u & 0x80000000u) ? ~u : (u | 0x80000000u);   // order-preserving flip
    key[i] = ((unsigned long long)u << 32) | (0xFFFFFFFFu - (unsigned)i);
  }
  __syncthreads();
  for (int size = 2; size <= n; size <<= 1) {
    for (int stride = size >> 1; stride > 0; stride >>= 1) {
      for (int i = tid; i < n; i += 1024) {
        int j = i ^ stride;
        if (j > i) {
          unsigned long long ka = key[i], kb = key[j];
          bool up = ((i & size) == 0);
          bool pj = kb > ka;
          if (up ? pj : !pj) { key[i] = kb; key[j] = ka; }
        }
      }
      __syncthreads();
    }
  }
  for (int i = tid; i < k; i += 1024) {
    unsigned long long kk = key[i];
    unsigned u = (unsigned)(kk >> 32);
    u = (u & 0x80000000u) ? (u & 0x7FFFFFFFu) : ~u;
    perm[i] = (int)(0xFFFFFFFFu - (unsigned)(kk & 0xFFFFFFFFu));
    vals[i] = __uint_as_float(u);
  }
}

// xo[i,:] = x[perm[i],:] * vals[i]
__global__ void pool_x(const float* __restrict__ x, const int* __restrict__ perm,
                       const float* __restrict__ vals, float* __restrict__ xo) {
  int i = blockIdx.x, c = threadIdx.x;
  xo[(size_t)i * CH + c] = x[(size_t)perm[i] * CH + c] * vals[i];
}

// ---------------- augment operand gathers (diag forced to 1 inline) ----------------

// O[m][0:n] = bf16(A[perm[m]][0:n]), entry at col==perm[m] -> 1.0
__global__ void rowgather_cvt(const float* __restrict__ A, const int* __restrict__ perm,
                              int n, ushort* __restrict__ O) {
  int m = blockIdx.y;
  int src = perm[m];
  int k4 = (blockIdx.x * 256 + threadIdx.x) * 4;
  float4 v = *(const float4*)&A[(size_t)src * n + k4];
  if (src >= k4 && src < k4 + 4) ((float*)&v)[src - k4] = 1.0f;
  ushort4 o;
  o.x = f2bf(v.x); o.y = f2bf(v.y); o.z = f2bf(v.z); o.w = f2bf(v.w);
  *(ushort4*)&O[(size_t)m * n + k4] = o;
}

// O[m][0:n] = At[perm[m]][0:n] (bf16 copy), entry at col==perm[m] -> 1.0
__global__ void rowgather_bf16(const ushort* __restrict__ At, const int* __restrict__ perm,
                               int n, ushort* __restrict__ O) {
  int m = blockIdx.y;
  int src = perm[m];
  int k8 = (blockIdx.x * 256 + threadIdx.x) * 8;
  uint4 v = *(const uint4*)&At[(size_t)src * n + k8];
  if (src >= k8 && src < k8 + 8) ((ushort*)&v)[src - k8] = 0x3F80;  // bf16(1.0)
  *(uint4*)&O[(size_t)m * n + k8] = v;
}

// ---------------- unified bf16 MFMA NT GEMM: C[m][n] += sum_k A[m][k]*B[n][k] ----------------
// 128x128 tile, 2x2 waves (4x4 fragments each), BK=64, split-K via blockIdx.z,
// fp32 atomicAdd epilogue into zero-initialized C (ldc = output row stride).
__global__ __launch_bounds__(256) void mfma_nt(const ushort* __restrict__ A,
                                               const ushort* __restrict__ B,
                                               float* __restrict__ C, int ldc,
                                               int K, int kChunk) {
  __shared__ ushort As[128][72];
  __shared__ ushort Bs[128][72];
  const int tid = threadIdx.x;
  const int wave = tid >> 6, lane = tid & 63;
  const int wm = (wave & 1) * 64, wn = (wave >> 1) * 64;
  const int m0 = blockIdx.x * 128, n0 = blockIdx.y * 128;
  const int k0 = blockIdx.z * kChunk;
  const int lrow = lane & 15;
  const int kq = (lane >> 4) * 8;
  const int srow = tid >> 3, scol = (tid & 7) * 8;
  f32x4 acc[4][4] = {};

  for (int kt = k0; kt < k0 + kChunk; kt += 64) {
    __syncthreads();
#pragma unroll
    for (int r = 0; r < 4; ++r) {
      *(uint4*)&As[srow + r * 32][scol] = *(const uint4*)&A[(size_t)(m0 + srow + r * 32) * K + kt + scol];
      *(uint4*)&Bs[srow + r * 32][scol] = *(const uint4*)&B[(size_t)(n0 + srow + r * 32) * K + kt + scol];
    }
    __syncthreads();
#pragma unroll
    for (int ks = 0; ks < 2; ++ks) {
      short8 af[4], bf[4];
#pragma unroll
      for (int t = 0; t < 4; ++t) {
        af[t] = *(const short8*)&As[wm + t * 16 + lrow][ks * 32 + kq];
        bf[t] = *(const short8*)&Bs[wn + t * 16 + lrow][ks * 32 + kq];
      }
#pragma unroll
      for (int mt = 0; mt < 4; ++mt)
#pragma unroll
        for (int nt = 0; nt < 4; ++nt)
          acc[mt][nt] = __builtin_amdgcn_mfma_f32_16x16x32_bf16(af[mt], bf[nt], acc[mt][nt], 0, 0, 0);
    }
  }

  const int crow = (lane >> 4) * 4, ccol = lane & 15;
#pragma unroll
  for (int mt = 0; mt < 4; ++mt)
#pragma unroll
    for (int nt = 0; nt < 4; ++nt) {
      int gm = m0 + wm + mt * 16 + crow;
      int gn = n0 + wn + nt * 16 + ccol;
#pragma unroll
      for (int r = 0; r < 4; ++r)
        atomicAdd(&C[(size_t)(gm + r) * ldc + gn], acc[mt][nt][r]);
    }
}

// xo[m][c]=relu(dinv[m]*Cacc+bias); optional fused score: sc[m]=tanh(dot(xo[m],p)/||p||)
__global__ void agg_epilogue(const float* __restrict__ Cacc, const float* __restrict__ deg,
                             const float* __restrict__ bias, float* __restrict__ xo,
                             const float* __restrict__ p, float* __restrict__ sc) {
  int idx = blockIdx.x * 256 + threadIdx.x;
  int c4 = idx & 63;
  int m = idx >> 6;
  float d = deg[m];
  float s = (d > 0.f) ? 1.0f / sqrtf(d) : 0.f;
  float4 v = ((const float4*)Cacc)[idx];
  float4 b = ((const float4*)bias)[c4];
  v.x = fmaxf(fmaf(v.x, s, b.x), 0.f);
  v.y = fmaxf(fmaf(v.y, s, b.y), 0.f);
  v.z = fmaxf(fmaf(v.z, s, b.z), 0.f);
  v.w = fmaxf(fmaf(v.w, s, b.w), 0.f);
  ((float4*)xo)[idx] = v;
  if (p) {
    float4 pv = ((const float4*)p)[c4];
    float dot = v.x * pv.x + v.y * pv.y + v.z * pv.z + v.w * pv.w;
    float pn  = pv.x * pv.x + pv.y * pv.y + pv.z * pv.z + pv.w * pv.w;
    for (int off = 32; off; off >>= 1) {
      dot += __shfl_down(dot, off);
      pn  += __shfl_down(pn, off);
    }
    if ((threadIdx.x & 63) == 0) sc[m] = tanhf(dot / sqrtf(pn));
  }
}

// ---------------- fp32 xW GEMM -> Gt[n][m] = bf16(dinv[m]*(x@W)[m][n]) ----------------
__global__ __launch_bounds__(256) void xw_gemm(const float* __restrict__ Am,
                                               const float* __restrict__ Bm,
                                               ushort* __restrict__ Gt,
                                               int M, const float* __restrict__ deg) {
  __shared__ float As[16][64];
  __shared__ float Bs[16][64];
  const int tid = threadIdx.x;
  const int m0 = blockIdx.x * 64, n0 = blockIdx.y * 64;
  float acc[4][4] = {{0.f}};
  const int tm = tid & 15, tn = tid >> 4;

  for (int kt = 0; kt < CH; kt += 16) {
    __syncthreads();
    {
      int mm = tid >> 2, kq = (tid & 3) * 4;
      float4 v = *(const float4*)(Am + (size_t)(m0 + mm) * CH + kt + kq);
      As[kq + 0][mm] = v.x; As[kq + 1][mm] = v.y; As[kq + 2][mm] = v.z; As[kq + 3][mm] = v.w;
    }
#pragma unroll
    for (int r = 0; r < 4; ++r) {
      int idx = tid + r * 256;
      int kk = idx >> 6, nn = idx & 63;
      Bs[kk][nn] = Bm[(size_t)(kt + kk) * CH + (n0 + nn)];
    }
    __syncthreads();
#pragma unroll
    for (int kk = 0; kk < 16; ++kk) {
      float4 a = *(const float4*)&As[kk][tm * 4];
      float4 b = *(const float4*)&Bs[kk][tn * 4];
      acc[0][0] = fmaf(a.x, b.x, acc[0][0]);
      acc[0][1] = fmaf(a.x, b.y, acc[0][1]);
      acc[0][2] = fmaf(a.x, b.z, acc[0][2]);
      acc[0][3] = fmaf(a.x, b.w, acc[0][3]);
      acc[1][0] = fmaf(a.y, b.x, acc[1][0]);
      acc[1][1] = fmaf(a.y, b.y, acc[1][1]);
      acc[1][2] = fmaf(a.y, b.z, acc[1][2]);
      acc[1][3] = fmaf(a.y, b.w, acc[1][3]);
      acc[2][0] = fmaf(a.z, b.x, acc[2][0]);
      acc[2][1] = fmaf(a.z, b.y, acc[2][1]);
      acc[2][2] = fmaf(a.z, b.z, acc[2][2]);
      acc[2][3] = fmaf(a.z, b.w, acc[2][3]);
      acc[3][0] = fmaf(a.w, b.x, acc[3][0]);
      acc[3][1] = fmaf(a.w, b.y, acc[3][1]);
      acc[3][2] = fmaf(a.w, b.z, acc[3][2]);
      acc[3][3] = fmaf(a.w, b.w, acc[3][3]);
    }
  }

#pragma unroll
  for (int ii = 0; ii < 4; ++ii) {
    int m = m0 + tm * 4 + ii;
    float d = deg[m];
    float s = (d > 0.f) ? 1.0f / sqrtf(d) : 0.f;
#pragma unroll
    for (int jj = 0; jj < 4; ++jj) {
      int n = n0 + tn * 4 + jj;
      Gt[(size_t)n * M + m] = f2bf(s * acc[ii][jj]);
    }
  }
}

// ---------------- readout ----------------

__global__ void mean_partial(const float* __restrict__ x2, float* __restrict__ macc) {
  int c = threadIdx.x;
  int j0 = blockIdx.x * 16;
  float s = 0.f;
#pragma unroll
  for (int j = 0; j < 16; ++j) s += x2[(size_t)(j0 + j) * CH + c];
  atomicAdd(&macc[c], s);
}

__global__ __launch_bounds__(256) void finalize2(const float* __restrict__ macc, int nr,
                                                 const float* __restrict__ wc,
                                                 const float* __restrict__ bc,
                                                 float* __restrict__ out) {
  __shared__ float semb[256];
  __shared__ float red[256];
  __shared__ float slog[16];
  int c = threadIdx.x;
  float emb = macc[c] / (float)nr;
  red[c] = emb * emb;
  __syncthreads();
  for (int off = 128; off; off >>= 1) {
    if (c < off) red[c] += red[c + off];
    __syncthreads();
  }
  float denom = fmaxf(sqrtf(red[0]), 1e-12f);
  float en = emb / denom;
  semb[c] = en;
  out[c] = en;
  __syncthreads();
  if (c < 10) {
    float l = bc[c];
    for (int t = 0; t < CH; ++t) l = fmaf(semb[t], wc[c * CH + t], l);
    slog[c] = l;
  }
  __syncthreads();
  if (c == 0) {
    float mx = slog[0];
    for (int j = 1; j < 10; ++j) mx = fmaxf(mx, slog[j]);
    float se = 0.f;
    for (int j = 0; j < 10; ++j) se += expf(slog[j] - mx);
    float lse = mx + logf(se);
    for (int j = 0; j < 10; ++j) out[CH + j] = slog[j] - lse;
  }
}

// ---------------- orchestration ----------------

extern "C" void kernel_launch(void* const* d_in, const int* in_sizes, int n_in,
                              void* d_out, int out_size, void* d_ws, size_t ws_size,
                              hipStream_t stream) {
  const float* x  = (const float*)d_in[0];
  const int*   ei = (const int*)d_in[1];
  const float* w0 = (const float*)d_in[2];
  const float* b0 = (const float*)d_in[3];
  const float* w1 = (const float*)d_in[4];
  const float* b1 = (const float*)d_in[5];
  const float* w2 = (const float*)d_in[6];
  const float* b2 = (const float*)d_in[7];
  const float* p1 = (const float*)d_in[8];
  const float* p2 = (const float*)d_in[9];
  const float* wc = (const float*)d_in[10];
  const float* bc = (const float*)d_in[11];
  float* out = (float*)d_out;
  const int N0 = 4096, K1 = 2048, K2 = 1024;
  int E = in_sizes[1] / 2;

  float* W = (float*)d_ws;
  size_t off = 0;
  float* A    = W + off; off += (size_t)N0 * N0;                  // fp32 adj; later reused as Brow
  float* Pa   = W + off; off += (size_t)K1 * K1;
  float* Pb   = W + off; off += (size_t)K2 * K2;
  ushort* At  = (ushort*)(W + off); off += (size_t)N0 * N0 / 2;   // bf16 transposed adj (per level)
  ushort* Arow = (ushort*)(W + off); off += (size_t)K1 * N0 / 2;  // bf16 gathered rows
  ushort* Brow = (ushort*)A;                                      // aliases A (dead by then)
  float* x0   = W + off; off += (size_t)N0 * CH;
  float* Cacc = W + off; off += (size_t)N0 * CH;
  ushort* Gt  = (ushort*)(W + off); off += (size_t)N0 * CH / 2;
  float* xp  = W + off; off += (size_t)K1 * CH;
  float* x1  = W + off; off += (size_t)K1 * CH;
  float* x2  = W + off; off += (size_t)K2 * CH;
  float* sc  = W + off; off += 4096;
  float* vals = W + off; off += 4096;
  float* deg  = W + off; off += 4096;
  float* macc = W + off; off += 256;
  int* perm1 = (int*)(W + off); off += 4096;
  int* perm2 = (int*)(W + off); off += 4096;

  // ---- build adjacency ----
  hipMemsetAsync(A, 0, (size_t)N0 * N0 * 4, stream);
  scatter_edges<<<(E + 255) / 256, 256, 0, stream>>>(ei, E, N0, A);

  // ---- GCN 0 ----
  hipMemsetAsync(deg, 0, N0 * 4, stream);
  transpose_deg<0><<<dim3(N0 / 64, N0 / 64), 256, 0, stream>>>(A, N0, At, deg);
  xw_gemm<<<dim3(N0 / 64, CH / 64), 256, 0, stream>>>(x, w0, Gt, N0, deg);
  hipMemsetAsync(Cacc, 0, (size_t)N0 * CH * 4, stream);
  mfma_nt<<<dim3(N0 / 128, CH / 128, 4), 256, 0, stream>>>(At, Gt, Cacc, CH, N0, N0 / 4);
  agg_epilogue<<<N0 / 4, 256, 0, stream>>>(Cacc, deg, b0, x0, p1, sc);

  // ---- pool 1 ----
  topk_sort<<<1, 1024, 0, stream>>>(sc, N0, K1, perm1, vals);

  // ---- augment L1: Pa = (B@B)[perm1][:,perm1], B = A w/ diag 1 (bf16 MFMA, exact) ----
  rowgather_cvt<<<dim3(N0 / 1024, K1), 256, 0, stream>>>(A, perm1, N0, Arow);
  rowgather_bf16<<<dim3(N0 / 2048, K1), 256, 0, stream>>>(At, perm1, N0, Brow);
  hipMemsetAsync(Pa, 0, (size_t)K1 * K1 * 4, stream);
  mfma_nt<<<dim3(K1 / 128, K1 / 128, 2), 256, 0, stream>>>(Arow, Brow, Pa, K1, N0, N0 / 2);
  pool_x<<<K1, 256, 0, stream>>>(x0, perm1, vals, xp);

  // ---- GCN 1 ----
  hipMemsetAsync(deg, 0, K1 * 4, stream);
  transpose_deg<1><<<dim3(K1 / 64, K1 / 64), 256, 0, stream>>>(Pa, K1, At, deg);
  xw_gemm<<<dim3(K1 / 64, CH / 64), 256, 0, stream>>>(xp, w1, Gt, K1, deg);
  hipMemsetAsync(Cacc, 0, (size_t)K1 * CH * 4, stream);
  mfma_nt<<<dim3(K1 / 128, CH / 128, 8), 256, 0, stream>>>(At, Gt, Cacc, CH, K1, K1 / 8);
  agg_epilogue<<<K1 / 4, 256, 0, stream>>>(Cacc, deg, b1, x1, p2, sc);

  // ---- pool 2 ----
  topk_sort<<<1, 1024, 0, stream>>>(sc, K1, K2, perm2, vals);

  // ---- augment L2 ----
  rowgather_cvt<<<dim3(K1 / 1024, K2), 256, 0, stream>>>(Pa, perm2, K1, Arow);
  rowgather_bf16<<<dim3(K1 / 2048, K2), 256, 0, stream>>>(At, perm2, K1, Brow);
  hipMemsetAsync(Pb, 0, (size_t)K2 * K2 * 4, stream);
  mfma_nt<<<dim3(K2 / 128, K2 / 128, 4), 256, 0, stream>>>(Arow, Brow, Pb, K2, K1, K1 / 4);
  pool_x<<<K2, 256, 0, stream>>>(x1, perm2, vals, xp);

  // ---- GCN 2 ----
  hipMemsetAsync(deg, 0, K2 * 4, stream);
  transpose_deg<1><<<dim3(K2 / 64, K2 / 64), 256, 0, stream>>>(Pb, K2, At, deg);
  xw_gemm<<<dim3(K2 / 64, CH / 64), 256, 0, stream>>>(xp, w2, Gt, K2, deg);
  hipMemsetAsync(Cacc, 0, (size_t)K2 * CH * 4, stream);
  mfma_nt<<<dim3(K2 / 128, CH / 128, 8), 256, 0, stream>>>(At, Gt, Cacc, CH, K2, K2 / 8);
  agg_epilogue<<<K2 / 4, 256, 0, stream>>>(Cacc, deg, b2, x2, nullptr, nullptr);

  // ---- readout ----
  hipMemsetAsync(macc, 0, 256 * 4, stream);
  mean_partial<<<K2 / 16, 256, 0, stream>>>(x2, macc);
  finalize2<<<1, 256, 0, stream>>>(macc, K2, wc, bc, out);
}

// Round 8
// 565.028 us; speedup vs baseline: 1.0041x; 1.0041x over previous
//
#include <hip/hip_runtime.h>
#include <math.h>

#define CH 256

typedef short short8 __attribute__((ext_vector_type(8)));
typedef float f32x4 __attribute__((ext_vector_type(4)));

// f32 -> bf16 bits (RNE); adjacency values are small ints, exact
__device__ inline ushort f2bf(float f) {
  unsigned u = __float_as_uint(f);
  unsigned r = (u + 0x7FFFu + ((u >> 16) & 1u)) >> 16;
  return (ushort)r;
}

// ---------------- build ----------------

__global__ void scatter_edges(const int* __restrict__ ei, int E, int n, float* __restrict__ A) {
  int e = blockIdx.x * blockDim.x + threadIdx.x;
  if (e < E) atomicAdd(&A[(size_t)ei[e] * n + ei[E + e]], 1.0f);
}

// ---------------- fused transpose + diag rule + column-degree ----------------
// DIAGMODE 0: diag v==0 -> 2.0 (GCN rule on raw A); DIAGMODE 1: diag forced 2.0 (post-augment)
template <int DIAGMODE>
__global__ __launch_bounds__(256) void transpose_deg(const float* __restrict__ In, int n,
                                                     ushort* __restrict__ O, float* __restrict__ deg) {
  __shared__ float t[64][65];
  int j0 = blockIdx.x * 64, i0 = blockIdx.y * 64;
  int tx = threadIdx.x & 63, ty4 = threadIdx.x >> 6;
  float s = 0.f;
#pragma unroll
  for (int r = 0; r < 64; r += 4) {
    int gi = i0 + ty4 + r, gj = j0 + tx;
    float v = In[(size_t)gi * n + gj];
    if (gi == gj) v = (DIAGMODE == 1) ? 2.0f : ((v != 0.f) ? v : 2.0f);
    t[ty4 + r][tx] = v;
    s += v;
  }
  atomicAdd(&deg[j0 + tx], s);
  __syncthreads();
#pragma unroll
  for (int r = 0; r < 64; r += 4) {
    int c = ty4 + r;
    O[(size_t)(j0 + c) * n + i0 + tx] = f2bf(t[tx][c]);
  }
}

// ---------------- top-k: bitonic sort on packed u64 (desc score, asc index) ----------------
__global__ __launch_bounds__(1024) void topk_sort(const float* __restrict__ sc, int n, int k,
                                                  int* __restrict__ perm, float* __restrict__ vals) {
  __shared__ unsigned long long key[4096];
  int tid = threadIdx.x;
  for (int i = tid; i < n; i += 1024) {
    unsigned u = __float_as_uint(sc[i]);
    u = (u & 0x80000000u) ? ~u : (u | 0x80000000u);   // order-preserving flip
    key[i] = ((unsigned long long)u << 32) | (0xFFFFFFFFu - (unsigned)i);
  }
  __syncthreads();
  for (int size = 2; size <= n; size <<= 1) {
    for (int stride = size >> 1; stride > 0; stride >>= 1) {
      for (int i = tid; i < n; i += 1024) {
        int j = i ^ stride;
        if (j > i) {
          unsigned long long ka = key[i], kb = key[j];
          bool up = ((i & size) == 0);
          bool pj = kb > ka;
          if (up ? pj : !pj) { key[i] = kb; key[j] = ka; }
        }
      }
      __syncthreads();
    }
  }
  for (int i = tid; i < k; i += 1024) {
    unsigned long long kk = key[i];
    unsigned u = (unsigned)(kk >> 32);
    u = (u & 0x80000000u) ? (u & 0x7FFFFFFFu) : ~u;
    perm[i] = (int)(0xFFFFFFFFu - (unsigned)(kk & 0xFFFFFFFFu));
    vals[i] = __uint_as_float(u);
  }
}

// xo[i,:] = x[perm[i],:] * vals[i]
__global__ void pool_x(const float* __restrict__ x, const int* __restrict__ perm,
                       const float* __restrict__ vals, float* __restrict__ xo) {
  int i = blockIdx.x, c = threadIdx.x;
  xo[(size_t)i * CH + c] = x[(size_t)perm[i] * CH + c] * vals[i];
}

// ---------------- augment operand gathers (diag forced to 1 inline) ----------------

// O[m][0:n] = bf16(A[perm[m]][0:n]), entry at col==perm[m] -> 1.0
__global__ void rowgather_cvt(const float* __restrict__ A, const int* __restrict__ perm,
                              int n, ushort* __restrict__ O) {
  int m = blockIdx.y;
  int src = perm[m];
  int k4 = (blockIdx.x * 256 + threadIdx.x) * 4;
  float4 v = *(const float4*)&A[(size_t)src * n + k4];
  if (src >= k4 && src < k4 + 4) ((float*)&v)[src - k4] = 1.0f;
  ushort4 o;
  o.x = f2bf(v.x); o.y = f2bf(v.y); o.z = f2bf(v.z); o.w = f2bf(v.w);
  *(ushort4*)&O[(size_t)m * n + k4] = o;
}

// O[m][0:n] = At[perm[m]][0:n] (bf16 copy), entry at col==perm[m] -> 1.0
__global__ void rowgather_bf16(const ushort* __restrict__ At, const int* __restrict__ perm,
                               int n, ushort* __restrict__ O) {
  int m = blockIdx.y;
  int src = perm[m];
  int k8 = (blockIdx.x * 256 + threadIdx.x) * 8;
  uint4 v = *(const uint4*)&At[(size_t)src * n + k8];
  if (src >= k8 && src < k8 + 8) ((ushort*)&v)[src - k8] = 0x3F80;  // bf16(1.0)
  *(uint4*)&O[(size_t)m * n + k8] = v;
}

// ---------------- bf16 MFMA NT GEMM, fat wave tiles ----------------
// Block = 128 threads (2 waves). Block tile 128(M) x 128(N); each wave computes
// 128x64 via 8x4 fragments of 16x16x32 -> 2x the FLOP per ds_read vs 4x4.
// ATOMIC=1: split-K via blockIdx.z with fp32 atomicAdd into zeroed C.
template <int ATOMIC>
__global__ __launch_bounds__(128) void mfma_nt(const ushort* __restrict__ A,
                                               const ushort* __restrict__ B,
                                               float* __restrict__ C, int ldc,
                                               int K, int kChunk) {
  __shared__ ushort As[128][72];
  __shared__ ushort Bs[128][72];
  const int tid = threadIdx.x;
  const int wave = tid >> 6, lane = tid & 63;
  const int wn = wave * 64;
  const int m0 = blockIdx.x * 128, n0 = blockIdx.y * 128;
  const int k0 = ATOMIC ? blockIdx.z * kChunk : 0;
  const int kEnd = ATOMIC ? (k0 + kChunk) : K;
  const int lrow = lane & 15;
  const int kq = (lane >> 4) * 8;
  f32x4 acc[8][4] = {};

  for (int kt = k0; kt < kEnd; kt += 64) {
    __syncthreads();
#pragma unroll
    for (int r = 0; r < 8; ++r) {
      int c = tid + r * 128;              // 1024 chunks of 8 bf16 each
      int row = c >> 3, col8 = (c & 7) * 8;
      *(uint4*)&As[row][col8] = *(const uint4*)&A[(size_t)(m0 + row) * K + kt + col8];
      *(uint4*)&Bs[row][col8] = *(const uint4*)&B[(size_t)(n0 + row) * K + kt + col8];
    }
    __syncthreads();
#pragma unroll
    for (int ks = 0; ks < 2; ++ks) {
      short8 af[8], bf[4];
#pragma unroll
      for (int t = 0; t < 8; ++t)
        af[t] = *(const short8*)&As[t * 16 + lrow][ks * 32 + kq];
#pragma unroll
      for (int t = 0; t < 4; ++t)
        bf[t] = *(const short8*)&Bs[wn + t * 16 + lrow][ks * 32 + kq];
#pragma unroll
      for (int mt = 0; mt < 8; ++mt)
#pragma unroll
        for (int nt = 0; nt < 4; ++nt)
          acc[mt][nt] = __builtin_amdgcn_mfma_f32_16x16x32_bf16(af[mt], bf[nt], acc[mt][nt], 0, 0, 0);
    }
  }

  const int crow = (lane >> 4) * 4, ccol = lane & 15;
#pragma unroll
  for (int mt = 0; mt < 8; ++mt)
#pragma unroll
    for (int nt = 0; nt < 4; ++nt) {
      int gm = m0 + mt * 16 + crow;
      int gn = n0 + wn + nt * 16 + ccol;
#pragma unroll
      for (int r = 0; r < 4; ++r) {
        if (ATOMIC) atomicAdd(&C[(size_t)(gm + r) * ldc + gn], acc[mt][nt][r]);
        else        C[(size_t)(gm + r) * ldc + gn] = acc[mt][nt][r];
      }
    }
}

// xo[m][c]=relu(dinv[m]*Cacc+bias); optional fused score: sc[m]=tanh(dot(xo[m],p)/||p||)
__global__ void agg_epilogue(const float* __restrict__ Cacc, const float* __restrict__ deg,
                             const float* __restrict__ bias, float* __restrict__ xo,
                             const float* __restrict__ p, float* __restrict__ sc) {
  int idx = blockIdx.x * 256 + threadIdx.x;
  int c4 = idx & 63;
  int m = idx >> 6;
  float d = deg[m];
  float s = (d > 0.f) ? 1.0f / sqrtf(d) : 0.f;
  float4 v = ((const float4*)Cacc)[idx];
  float4 b = ((const float4*)bias)[c4];
  v.x = fmaxf(fmaf(v.x, s, b.x), 0.f);
  v.y = fmaxf(fmaf(v.y, s, b.y), 0.f);
  v.z = fmaxf(fmaf(v.z, s, b.z), 0.f);
  v.w = fmaxf(fmaf(v.w, s, b.w), 0.f);
  ((float4*)xo)[idx] = v;
  if (p) {
    float4 pv = ((const float4*)p)[c4];
    float dot = v.x * pv.x + v.y * pv.y + v.z * pv.z + v.w * pv.w;
    float pn  = pv.x * pv.x + pv.y * pv.y + pv.z * pv.z + pv.w * pv.w;
    for (int off = 32; off; off >>= 1) {
      dot += __shfl_down(dot, off);
      pn  += __shfl_down(pn, off);
    }
    if ((threadIdx.x & 63) == 0) sc[m] = tanhf(dot / sqrtf(pn));
  }
}

// ---------------- fp32 xW GEMM -> Gt[n][m] = bf16(dinv[m]*(x@W)[m][n]) ----------------
__global__ __launch_bounds__(256) void xw_gemm(const float* __restrict__ Am,
                                               const float* __restrict__ Bm,
                                               ushort* __restrict__ Gt,
                                               int M, const float* __restrict__ deg) {
  __shared__ float As[16][64];
  __shared__ float Bs[16][64];
  const int tid = threadIdx.x;
  const int m0 = blockIdx.x * 64, n0 = blockIdx.y * 64;
  float acc[4][4] = {{0.f}};
  const int tm = tid & 15, tn = tid >> 4;

  for (int kt = 0; kt < CH; kt += 16) {
    __syncthreads();
    {
      int mm = tid >> 2, kq = (tid & 3) * 4;
      float4 v = *(const float4*)(Am + (size_t)(m0 + mm) * CH + kt + kq);
      As[kq + 0][mm] = v.x; As[kq + 1][mm] = v.y; As[kq + 2][mm] = v.z; As[kq + 3][mm] = v.w;
    }
#pragma unroll
    for (int r = 0; r < 4; ++r) {
      int idx = tid + r * 256;
      int kk = idx >> 6, nn = idx & 63;
      Bs[kk][nn] = Bm[(size_t)(kt + kk) * CH + (n0 + nn)];
    }
    __syncthreads();
#pragma unroll
    for (int kk = 0; kk < 16; ++kk) {
      float4 a = *(const float4*)&As[kk][tm * 4];
      float4 b = *(const float4*)&Bs[kk][tn * 4];
      acc[0][0] = fmaf(a.x, b.x, acc[0][0]);
      acc[0][1] = fmaf(a.x, b.y, acc[0][1]);
      acc[0][2] = fmaf(a.x, b.z, acc[0][2]);
      acc[0][3] = fmaf(a.x, b.w, acc[0][3]);
      acc[1][0] = fmaf(a.y, b.x, acc[1][0]);
      acc[1][1] = fmaf(a.y, b.y, acc[1][1]);
      acc[1][2] = fmaf(a.y, b.z, acc[1][2]);
      acc[1][3] = fmaf(a.y, b.w, acc[1][3]);
      acc[2][0] = fmaf(a.z, b.x, acc[2][0]);
      acc[2][1] = fmaf(a.z, b.y, acc[2][1]);
      acc[2][2] = fmaf(a.z, b.z, acc[2][2]);
      acc[2][3] = fmaf(a.z, b.w, acc[2][3]);
      acc[3][0] = fmaf(a.w, b.x, acc[3][0]);
      acc[3][1] = fmaf(a.w, b.y, acc[3][1]);
      acc[3][2] = fmaf(a.w, b.z, acc[3][2]);
      acc[3][3] = fmaf(a.w, b.w, acc[3][3]);
    }
  }

#pragma unroll
  for (int ii = 0; ii < 4; ++ii) {
    int m = m0 + tm * 4 + ii;
    float d = deg[m];
    float s = (d > 0.f) ? 1.0f / sqrtf(d) : 0.f;
#pragma unroll
    for (int jj = 0; jj < 4; ++jj) {
      int n = n0 + tn * 4 + jj;
      Gt[(size_t)n * M + m] = f2bf(s * acc[ii][jj]);
    }
  }
}

// ---------------- readout ----------------

__global__ void mean_partial(const float* __restrict__ x2, float* __restrict__ macc) {
  int c = threadIdx.x;
  int j0 = blockIdx.x * 16;
  float s = 0.f;
#pragma unroll
  for (int j = 0; j < 16; ++j) s += x2[(size_t)(j0 + j) * CH + c];
  atomicAdd(&macc[c], s);
}

__global__ __launch_bounds__(256) void finalize2(const float* __restrict__ macc, int nr,
                                                 const float* __restrict__ wc,
                                                 const float* __restrict__ bc,
                                                 float* __restrict__ out) {
  __shared__ float semb[256];
  __shared__ float red[256];
  __shared__ float slog[16];
  int c = threadIdx.x;
  float emb = macc[c] / (float)nr;
  red[c] = emb * emb;
  __syncthreads();
  for (int off = 128; off; off >>= 1) {
    if (c < off) red[c] += red[c + off];
    __syncthreads();
  }
  float denom = fmaxf(sqrtf(red[0]), 1e-12f);
  float en = emb / denom;
  semb[c] = en;
  out[c] = en;
  __syncthreads();
  if (c < 10) {
    float l = bc[c];
    for (int t = 0; t < CH; ++t) l = fmaf(semb[t], wc[c * CH + t], l);
    slog[c] = l;
  }
  __syncthreads();
  if (c == 0) {
    float mx = slog[0];
    for (int j = 1; j < 10; ++j) mx = fmaxf(mx, slog[j]);
    float se = 0.f;
    for (int j = 0; j < 10; ++j) se += expf(slog[j] - mx);
    float lse = mx + logf(se);
    for (int j = 0; j < 10; ++j) out[CH + j] = slog[j] - lse;
  }
}

// ---------------- orchestration ----------------

extern "C" void kernel_launch(void* const* d_in, const int* in_sizes, int n_in,
                              void* d_out, int out_size, void* d_ws, size_t ws_size,
                              hipStream_t stream) {
  const float* x  = (const float*)d_in[0];
  const int*   ei = (const int*)d_in[1];
  const float* w0 = (const float*)d_in[2];
  const float* b0 = (const float*)d_in[3];
  const float* w1 = (const float*)d_in[4];
  const float* b1 = (const float*)d_in[5];
  const float* w2 = (const float*)d_in[6];
  const float* b2 = (const float*)d_in[7];
  const float* p1 = (const float*)d_in[8];
  const float* p2 = (const float*)d_in[9];
  const float* wc = (const float*)d_in[10];
  const float* bc = (const float*)d_in[11];
  float* out = (float*)d_out;
  const int N0 = 4096, K1 = 2048, K2 = 1024;
  int E = in_sizes[1] / 2;

  float* W = (float*)d_ws;
  size_t off = 0;
  float* A    = W + off; off += (size_t)N0 * N0;                  // fp32 adj; later reused as Brow
  float* Pa   = W + off; off += (size_t)K1 * K1;
  float* Pb   = W + off; off += (size_t)K2 * K2;
  ushort* At  = (ushort*)(W + off); off += (size_t)N0 * N0 / 2;   // bf16 transposed adj (per level)
  ushort* Arow = (ushort*)(W + off); off += (size_t)K1 * N0 / 2;  // bf16 gathered rows
  ushort* Brow = (ushort*)A;                                      // aliases A (dead by then)
  float* x0   = W + off; off += (size_t)N0 * CH;
  float* Cacc = W + off; off += (size_t)N0 * CH;
  ushort* Gt  = (ushort*)(W + off); off += (size_t)N0 * CH / 2;
  float* xp  = W + off; off += (size_t)K1 * CH;
  float* x1  = W + off; off += (size_t)K1 * CH;
  float* x2  = W + off; off += (size_t)K2 * CH;
  float* sc  = W + off; off += 4096;
  float* vals = W + off; off += 4096;
  float* deg  = W + off; off += 4096;
  float* macc = W + off; off += 256;
  int* perm1 = (int*)(W + off); off += 4096;
  int* perm2 = (int*)(W + off); off += 4096;

  // ---- build adjacency ----
  hipMemsetAsync(A, 0, (size_t)N0 * N0 * 4, stream);
  scatter_edges<<<(E + 255) / 256, 256, 0, stream>>>(ei, E, N0, A);

  // ---- GCN 0 ----
  hipMemsetAsync(deg, 0, N0 * 4, stream);
  transpose_deg<0><<<dim3(N0 / 64, N0 / 64), 256, 0, stream>>>(A, N0, At, deg);
  xw_gemm<<<dim3(N0 / 64, CH / 64), 256, 0, stream>>>(x, w0, Gt, N0, deg);
  hipMemsetAsync(Cacc, 0, (size_t)N0 * CH * 4, stream);
  mfma_nt<1><<<dim3(N0 / 128, CH / 128, 8), 128, 0, stream>>>(At, Gt, Cacc, CH, N0, N0 / 8);
  agg_epilogue<<<N0 / 4, 256, 0, stream>>>(Cacc, deg, b0, x0, p1, sc);

  // ---- pool 1 ----
  topk_sort<<<1, 1024, 0, stream>>>(sc, N0, K1, perm1, vals);

  // ---- augment L1: Pa = (B@B)[perm1][:,perm1], B = A w/ diag 1 (bf16 MFMA, exact) ----
  rowgather_cvt<<<dim3(N0 / 1024, K1), 256, 0, stream>>>(A, perm1, N0, Arow);
  rowgather_bf16<<<dim3(N0 / 2048, K1), 256, 0, stream>>>(At, perm1, N0, Brow);
  mfma_nt<0><<<dim3(K1 / 128, K1 / 128, 1), 128, 0, stream>>>(Arow, Brow, Pa, K1, N0, N0);
  pool_x<<<K1, 256, 0, stream>>>(x0, perm1, vals, xp);

  // ---- GCN 1 ----
  hipMemsetAsync(deg, 0, K1 * 4, stream);
  transpose_deg<1><<<dim3(K1 / 64, K1 / 64), 256, 0, stream>>>(Pa, K1, At, deg);
  xw_gemm<<<dim3(K1 / 64, CH / 64), 256, 0, stream>>>(xp, w1, Gt, K1, deg);
  hipMemsetAsync(Cacc, 0, (size_t)K1 * CH * 4, stream);
  mfma_nt<1><<<dim3(K1 / 128, CH / 128, 8), 128, 0, stream>>>(At, Gt, Cacc, CH, K1, K1 / 8);
  agg_epilogue<<<K1 / 4, 256, 0, stream>>>(Cacc, deg, b1, x1, p2, sc);

  // ---- pool 2 ----
  topk_sort<<<1, 1024, 0, stream>>>(sc, K1, K2, perm2, vals);

  // ---- augment L2 ----
  rowgather_cvt<<<dim3(K1 / 1024, K2), 256, 0, stream>>>(Pa, perm2, K1, Arow);
  rowgather_bf16<<<dim3(K1 / 2048, K2), 256, 0, stream>>>(At, perm2, K1, Brow);
  hipMemsetAsync(Pb, 0, (size_t)K2 * K2 * 4, stream);
  mfma_nt<1><<<dim3(K2 / 128, K2 / 128, 4), 128, 0, stream>>>(Arow, Brow, Pb, K2, K1, K1 / 4);
  pool_x<<<K2, 256, 0, stream>>>(x1, perm2, vals, xp);

  // ---- GCN 2 ----
  hipMemsetAsync(deg, 0, K2 * 4, stream);
  transpose_deg<1><<<dim3(K2 / 64, K2 / 64), 256, 0, stream>>>(Pb, K2, At, deg);
  xw_gemm<<<dim3(K2 / 64, CH / 64), 256, 0, stream>>>(xp, w2, Gt, K2, deg);
  hipMemsetAsync(Cacc, 0, (size_t)K2 * CH * 4, stream);
  mfma_nt<1><<<dim3(K2 / 128, CH / 128, 16), 128, 0, stream>>>(At, Gt, Cacc, CH, K2, K2 / 16);
  agg_epilogue<<<K2 / 4, 256, 0, stream>>>(Cacc, deg, b2, x2, nullptr, nullptr);

  // ---- readout ----
  hipMemsetAsync(macc, 0, 256 * 4, stream);
  mean_partial<<<K2 / 16, 256, 0, stream>>>(x2, macc);
  finalize2<<<1, 256, 0, stream>>>(macc, K2, wc, bc, out);
}

// Round 9
// 519.746 us; speedup vs baseline: 1.0916x; 1.0871x over previous
//
#include <hip/hip_runtime.h>
#include <math.h>

#define CH 256

typedef short short8 __attribute__((ext_vector_type(8)));
typedef float f32x4 __attribute__((ext_vector_type(4)));

// f32 -> bf16 bits (RNE); adjacency values are small ints, exact
__device__ inline ushort f2bf(float f) {
  unsigned u = __float_as_uint(f);
  unsigned r = (u + 0x7FFFu + ((u >> 16) & 1u)) >> 16;
  return (ushort)r;
}

// async global->LDS DMA, 16B per lane; lds dest = wave-uniform base + lane*16
__device__ __forceinline__ void gld_lds16(const ushort* g, ushort* l) {
  __builtin_amdgcn_global_load_lds(
      (const __attribute__((address_space(1))) unsigned int*)g,
      (__attribute__((address_space(3))) unsigned int*)l, 16, 0, 0);
}

// ---------------- build ----------------

__global__ void scatter_edges(const int* __restrict__ ei, int E, int n, float* __restrict__ A) {
  int e = blockIdx.x * blockDim.x + threadIdx.x;
  if (e < E) atomicAdd(&A[(size_t)ei[e] * n + ei[E + e]], 1.0f);
}

// ---------------- fused transpose + diag rule + column-degree ----------------
// DIAGMODE 0: diag v==0 -> 2.0 (GCN rule on raw A); DIAGMODE 1: diag forced 2.0 (post-augment)
template <int DIAGMODE>
__global__ __launch_bounds__(256) void transpose_deg(const float* __restrict__ In, int n,
                                                     ushort* __restrict__ O, float* __restrict__ deg) {
  __shared__ float t[64][65];
  int j0 = blockIdx.x * 64, i0 = blockIdx.y * 64;
  int tx = threadIdx.x & 63, ty4 = threadIdx.x >> 6;
  float s = 0.f;
#pragma unroll
  for (int r = 0; r < 64; r += 4) {
    int gi = i0 + ty4 + r, gj = j0 + tx;
    float v = In[(size_t)gi * n + gj];
    if (gi == gj) v = (DIAGMODE == 1) ? 2.0f : ((v != 0.f) ? v : 2.0f);
    t[ty4 + r][tx] = v;
    s += v;
  }
  atomicAdd(&deg[j0 + tx], s);
  __syncthreads();
#pragma unroll
  for (int r = 0; r < 64; r += 4) {
    int c = ty4 + r;
    O[(size_t)(j0 + c) * n + i0 + tx] = f2bf(t[tx][c]);
  }
}

// ---------------- top-k: bitonic sort on packed u64 (desc score, asc index) ----------------
__global__ __launch_bounds__(1024) void topk_sort(const float* __restrict__ sc, int n, int k,
                                                  int* __restrict__ perm, float* __restrict__ vals) {
  __shared__ unsigned long long key[4096];
  int tid = threadIdx.x;
  for (int i = tid; i < n; i += 1024) {
    unsigned u = __float_as_uint(sc[i]);
    u = (u & 0x80000000u) ? ~u : (u | 0x80000000u);   // order-preserving flip
    key[i] = ((unsigned long long)u << 32) | (0xFFFFFFFFu - (unsigned)i);
  }
  __syncthreads();
  for (int size = 2; size <= n; size <<= 1) {
    for (int stride = size >> 1; stride > 0; stride >>= 1) {
      for (int i = tid; i < n; i += 1024) {
        int j = i ^ stride;
        if (j > i) {
          unsigned long long ka = key[i], kb = key[j];
          bool up = ((i & size) == 0);
          bool pj = kb > ka;
          if (up ? pj : !pj) { key[i] = kb; key[j] = ka; }
        }
      }
      __syncthreads();
    }
  }
  for (int i = tid; i < k; i += 1024) {
    unsigned long long kk = key[i];
    unsigned u = (unsigned)(kk >> 32);
    u = (u & 0x80000000u) ? (u & 0x7FFFFFFFu) : ~u;
    perm[i] = (int)(0xFFFFFFFFu - (unsigned)(kk & 0xFFFFFFFFu));
    vals[i] = __uint_as_float(u);
  }
}

// xo[i,:] = x[perm[i],:] * vals[i]
__global__ void pool_x(const float* __restrict__ x, const int* __restrict__ perm,
                       const float* __restrict__ vals, float* __restrict__ xo) {
  int i = blockIdx.x, c = threadIdx.x;
  xo[(size_t)i * CH + c] = x[(size_t)perm[i] * CH + c] * vals[i];
}

// ---------------- augment operand gathers (diag forced to 1 inline) ----------------

// O[m][0:n] = bf16(A[perm[m]][0:n]), entry at col==perm[m] -> 1.0
__global__ void rowgather_cvt(const float* __restrict__ A, const int* __restrict__ perm,
                              int n, ushort* __restrict__ O) {
  int m = blockIdx.y;
  int src = perm[m];
  int k4 = (blockIdx.x * 256 + threadIdx.x) * 4;
  float4 v = *(const float4*)&A[(size_t)src * n + k4];
  if (src >= k4 && src < k4 + 4) ((float*)&v)[src - k4] = 1.0f;
  ushort4 o;
  o.x = f2bf(v.x); o.y = f2bf(v.y); o.z = f2bf(v.z); o.w = f2bf(v.w);
  *(ushort4*)&O[(size_t)m * n + k4] = o;
}

// O[m][0:n] = At[perm[m]][0:n] (bf16 copy), entry at col==perm[m] -> 1.0
__global__ void rowgather_bf16(const ushort* __restrict__ At, const int* __restrict__ perm,
                               int n, ushort* __restrict__ O) {
  int m = blockIdx.y;
  int src = perm[m];
  int k8 = (blockIdx.x * 256 + threadIdx.x) * 8;
  uint4 v = *(const uint4*)&At[(size_t)src * n + k8];
  if (src >= k8 && src < k8 + 8) ((ushort*)&v)[src - k8] = 0x3F80;  // bf16(1.0)
  *(uint4*)&O[(size_t)m * n + k8] = v;
}

// ---------------- bf16 MFMA NT GEMM (m97-style): C[m][n] += sum_k A[m][k]*B[n][k] ----------------
// 128x128 tile, BK=64, 256 thr (4 waves, 2x2 of 64x64), global_load_lds(16B) staging,
// XOR bank swizzle (slot pos of row r holds logical chunk pos^(r&7)),
// split-K via blockIdx.z, fp32 atomicAdd into zeroed C.
__global__ __launch_bounds__(256) void mfma_nt(const ushort* __restrict__ A,
                                               const ushort* __restrict__ B,
                                               float* __restrict__ C, int ldc,
                                               int K, int kChunk) {
  __shared__ ushort As[8192];   // 128 rows x 64 bf16, swizzled chunks of 8
  __shared__ ushort Bs[8192];
  const int tid = threadIdx.x;
  const int wave = tid >> 6, lane = tid & 63;
  const int wm = (wave & 1) * 64, wn = (wave >> 1) * 64;
  const int m0 = blockIdx.x * 128, n0 = blockIdx.y * 128;
  const int k0 = blockIdx.z * kChunk;
  const int lrow = lane & 15;
  const int q = lane >> 4;
  f32x4 acc[4][4] = {};

  // staging geometry: call r: cid = r*256+tid; row=cid>>3, slot=cid&7, logical k8 = slot^(row&7)
  size_t gOffA[4], gOffB[4];
  ushort* lA[4]; ushort* lB[4];
#pragma unroll
  for (int r = 0; r < 4; ++r) {
    int cid = r * 256 + tid;
    int row = cid >> 3, slot = cid & 7;
    int gk8 = slot ^ (row & 7);
    gOffA[r] = (size_t)(m0 + row) * K + gk8 * 8;
    gOffB[r] = (size_t)(n0 + row) * K + gk8 * 8;
    int wbase = (r * 256 + (tid & ~63)) * 8;     // wave-uniform ushort offset
    lA[r] = &As[wbase];
    lB[r] = &Bs[wbase];
  }

  for (int kt = k0; kt < k0 + kChunk; kt += 64) {
    __syncthreads();
#pragma unroll
    for (int r = 0; r < 4; ++r) gld_lds16(A + gOffA[r] + kt, lA[r]);
#pragma unroll
    for (int r = 0; r < 4; ++r) gld_lds16(B + gOffB[r] + kt, lB[r]);
    __syncthreads();   // compiler drains vmcnt before barrier
#pragma unroll
    for (int ks = 0; ks < 2; ++ks) {
      const int pos = (ks * 4 + q) ^ (lrow & 7);  // same for A and B rows (row&7 == lrow&7)
      short8 af[4], bf[4];
#pragma unroll
      for (int t = 0; t < 4; ++t) {
        af[t] = *(const short8*)&As[(wm + t * 16 + lrow) * 64 + pos * 8];
        bf[t] = *(const short8*)&Bs[(wn + t * 16 + lrow) * 64 + pos * 8];
      }
#pragma unroll
      for (int mt = 0; mt < 4; ++mt)
#pragma unroll
        for (int nt = 0; nt < 4; ++nt)
          acc[mt][nt] = __builtin_amdgcn_mfma_f32_16x16x32_bf16(af[mt], bf[nt], acc[mt][nt], 0, 0, 0);
    }
  }

  const int crow = (lane >> 4) * 4, ccol = lane & 15;
#pragma unroll
  for (int mt = 0; mt < 4; ++mt)
#pragma unroll
    for (int nt = 0; nt < 4; ++nt) {
      int gm = m0 + wm + mt * 16 + crow;
      int gn = n0 + wn + nt * 16 + ccol;
#pragma unroll
      for (int r = 0; r < 4; ++r)
        atomicAdd(&C[(size_t)(gm + r) * ldc + gn], acc[mt][nt][r]);
    }
}

// xo[m][c]=relu(dinv[m]*Cacc+bias); optional fused score: sc[m]=tanh(dot(xo[m],p)/||p||)
__global__ void agg_epilogue(const float* __restrict__ Cacc, const float* __restrict__ deg,
                             const float* __restrict__ bias, float* __restrict__ xo,
                             const float* __restrict__ p, float* __restrict__ sc) {
  int idx = blockIdx.x * 256 + threadIdx.x;
  int c4 = idx & 63;
  int m = idx >> 6;
  float d = deg[m];
  float s = (d > 0.f) ? 1.0f / sqrtf(d) : 0.f;
  float4 v = ((const float4*)Cacc)[idx];
  float4 b = ((const float4*)bias)[c4];
  v.x = fmaxf(fmaf(v.x, s, b.x), 0.f);
  v.y = fmaxf(fmaf(v.y, s, b.y), 0.f);
  v.z = fmaxf(fmaf(v.z, s, b.z), 0.f);
  v.w = fmaxf(fmaf(v.w, s, b.w), 0.f);
  ((float4*)xo)[idx] = v;
  if (p) {
    float4 pv = ((const float4*)p)[c4];
    float dot = v.x * pv.x + v.y * pv.y + v.z * pv.z + v.w * pv.w;
    float pn  = pv.x * pv.x + pv.y * pv.y + pv.z * pv.z + pv.w * pv.w;
    for (int off = 32; off; off >>= 1) {
      dot += __shfl_down(dot, off);
      pn  += __shfl_down(pn, off);
    }
    if ((threadIdx.x & 63) == 0) sc[m] = tanhf(dot / sqrtf(pn));
  }
}

// ---------------- fp32 xW GEMM -> Gt[n][m] = bf16(dinv[m]*(x@W)[m][n]) ----------------
__global__ __launch_bounds__(256) void xw_gemm(const float* __restrict__ Am,
                                               const float* __restrict__ Bm,
                                               ushort* __restrict__ Gt,
                                               int M, const float* __restrict__ deg) {
  __shared__ float As[16][64];
  __shared__ float Bs[16][64];
  const int tid = threadIdx.x;
  const int m0 = blockIdx.x * 64, n0 = blockIdx.y * 64;
  float acc[4][4] = {{0.f}};
  const int tm = tid & 15, tn = tid >> 4;

  for (int kt = 0; kt < CH; kt += 16) {
    __syncthreads();
    {
      int mm = tid >> 2, kq = (tid & 3) * 4;
      float4 v = *(const float4*)(Am + (size_t)(m0 + mm) * CH + kt + kq);
      As[kq + 0][mm] = v.x; As[kq + 1][mm] = v.y; As[kq + 2][mm] = v.z; As[kq + 3][mm] = v.w;
    }
#pragma unroll
    for (int r = 0; r < 4; ++r) {
      int idx = tid + r * 256;
      int kk = idx >> 6, nn = idx & 63;
      Bs[kk][nn] = Bm[(size_t)(kt + kk) * CH + (n0 + nn)];
    }
    __syncthreads();
#pragma unroll
    for (int kk = 0; kk < 16; ++kk) {
      float4 a = *(const float4*)&As[kk][tm * 4];
      float4 b = *(const float4*)&Bs[kk][tn * 4];
      acc[0][0] = fmaf(a.x, b.x, acc[0][0]);
      acc[0][1] = fmaf(a.x, b.y, acc[0][1]);
      acc[0][2] = fmaf(a.x, b.z, acc[0][2]);
      acc[0][3] = fmaf(a.x, b.w, acc[0][3]);
      acc[1][0] = fmaf(a.y, b.x, acc[1][0]);
      acc[1][1] = fmaf(a.y, b.y, acc[1][1]);
      acc[1][2] = fmaf(a.y, b.z, acc[1][2]);
      acc[1][3] = fmaf(a.y, b.w, acc[1][3]);
      acc[2][0] = fmaf(a.z, b.x, acc[2][0]);
      acc[2][1] = fmaf(a.z, b.y, acc[2][1]);
      acc[2][2] = fmaf(a.z, b.z, acc[2][2]);
      acc[2][3] = fmaf(a.z, b.w, acc[2][3]);
      acc[3][0] = fmaf(a.w, b.x, acc[3][0]);
      acc[3][1] = fmaf(a.w, b.y, acc[3][1]);
      acc[3][2] = fmaf(a.w, b.z, acc[3][2]);
      acc[3][3] = fmaf(a.w, b.w, acc[3][3]);
    }
  }

#pragma unroll
  for (int ii = 0; ii < 4; ++ii) {
    int m = m0 + tm * 4 + ii;
    float d = deg[m];
    float s = (d > 0.f) ? 1.0f / sqrtf(d) : 0.f;
#pragma unroll
    for (int jj = 0; jj < 4; ++jj) {
      int n = n0 + tn * 4 + jj;
      Gt[(size_t)n * M + m] = f2bf(s * acc[ii][jj]);
    }
  }
}

// ---------------- readout ----------------

__global__ void mean_partial(const float* __restrict__ x2, float* __restrict__ macc) {
  int c = threadIdx.x;
  int j0 = blockIdx.x * 16;
  float s = 0.f;
#pragma unroll
  for (int j = 0; j < 16; ++j) s += x2[(size_t)(j0 + j) * CH + c];
  atomicAdd(&macc[c], s);
}

__global__ __launch_bounds__(256) void finalize2(const float* __restrict__ macc, int nr,
                                                 const float* __restrict__ wc,
                                                 const float* __restrict__ bc,
                                                 float* __restrict__ out) {
  __shared__ float semb[256];
  __shared__ float red[256];
  __shared__ float slog[16];
  int c = threadIdx.x;
  float emb = macc[c] / (float)nr;
  red[c] = emb * emb;
  __syncthreads();
  for (int off = 128; off; off >>= 1) {
    if (c < off) red[c] += red[c + off];
    __syncthreads();
  }
  float denom = fmaxf(sqrtf(red[0]), 1e-12f);
  float en = emb / denom;
  semb[c] = en;
  out[c] = en;
  __syncthreads();
  if (c < 10) {
    float l = bc[c];
    for (int t = 0; t < CH; ++t) l = fmaf(semb[t], wc[c * CH + t], l);
    slog[c] = l;
  }
  __syncthreads();
  if (c == 0) {
    float mx = slog[0];
    for (int j = 1; j < 10; ++j) mx = fmaxf(mx, slog[j]);
    float se = 0.f;
    for (int j = 0; j < 10; ++j) se += expf(slog[j] - mx);
    float lse = mx + logf(se);
    for (int j = 0; j < 10; ++j) out[CH + j] = slog[j] - lse;
  }
}

// ---------------- orchestration ----------------

extern "C" void kernel_launch(void* const* d_in, const int* in_sizes, int n_in,
                              void* d_out, int out_size, void* d_ws, size_t ws_size,
                              hipStream_t stream) {
  const float* x  = (const float*)d_in[0];
  const int*   ei = (const int*)d_in[1];
  const float* w0 = (const float*)d_in[2];
  const float* b0 = (const float*)d_in[3];
  const float* w1 = (const float*)d_in[4];
  const float* b1 = (const float*)d_in[5];
  const float* w2 = (const float*)d_in[6];
  const float* b2 = (const float*)d_in[7];
  const float* p1 = (const float*)d_in[8];
  const float* p2 = (const float*)d_in[9];
  const float* wc = (const float*)d_in[10];
  const float* bc = (const float*)d_in[11];
  float* out = (float*)d_out;
  const int N0 = 4096, K1 = 2048, K2 = 1024;
  int E = in_sizes[1] / 2;

  float* W = (float*)d_ws;
  size_t off = 0;
  float* A    = W + off; off += (size_t)N0 * N0;                  // fp32 adj; later reused as Brow
  float* Pa   = W + off; off += (size_t)K1 * K1;
  float* Pb   = W + off; off += (size_t)K2 * K2;
  ushort* At  = (ushort*)(W + off); off += (size_t)N0 * N0 / 2;   // bf16 transposed adj (per level)
  ushort* Arow = (ushort*)(W + off); off += (size_t)K1 * N0 / 2;  // bf16 gathered rows
  ushort* Brow = (ushort*)A;                                      // aliases A (dead by then)
  float* x0   = W + off; off += (size_t)N0 * CH;
  float* Cacc = W + off; off += (size_t)N0 * CH;
  ushort* Gt  = (ushort*)(W + off); off += (size_t)N0 * CH / 2;
  float* xp  = W + off; off += (size_t)K1 * CH;
  float* x1  = W + off; off += (size_t)K1 * CH;
  float* x2  = W + off; off += (size_t)K2 * CH;
  float* sc  = W + off; off += 4096;
  float* vals = W + off; off += 4096;
  float* deg  = W + off; off += 4096;
  float* macc = W + off; off += 256;
  int* perm1 = (int*)(W + off); off += 4096;
  int* perm2 = (int*)(W + off); off += 4096;

  // ---- build adjacency ----
  hipMemsetAsync(A, 0, (size_t)N0 * N0 * 4, stream);
  scatter_edges<<<(E + 255) / 256, 256, 0, stream>>>(ei, E, N0, A);

  // ---- GCN 0 ----
  hipMemsetAsync(deg, 0, N0 * 4, stream);
  transpose_deg<0><<<dim3(N0 / 64, N0 / 64), 256, 0, stream>>>(A, N0, At, deg);
  xw_gemm<<<dim3(N0 / 64, CH / 64), 256, 0, stream>>>(x, w0, Gt, N0, deg);
  hipMemsetAsync(Cacc, 0, (size_t)N0 * CH * 4, stream);
  mfma_nt<<<dim3(N0 / 128, CH / 128, 4), 256, 0, stream>>>(At, Gt, Cacc, CH, N0, N0 / 4);
  agg_epilogue<<<N0 / 4, 256, 0, stream>>>(Cacc, deg, b0, x0, p1, sc);

  // ---- pool 1 ----
  topk_sort<<<1, 1024, 0, stream>>>(sc, N0, K1, perm1, vals);

  // ---- augment L1: Pa = (B@B)[perm1][:,perm1], B = A w/ diag 1 (bf16 MFMA, exact) ----
  rowgather_cvt<<<dim3(N0 / 1024, K1), 256, 0, stream>>>(A, perm1, N0, Arow);
  rowgather_bf16<<<dim3(N0 / 2048, K1), 256, 0, stream>>>(At, perm1, N0, Brow);
  hipMemsetAsync(Pa, 0, (size_t)K1 * K1 * 4, stream);
  mfma_nt<<<dim3(K1 / 128, K1 / 128, 2), 256, 0, stream>>>(Arow, Brow, Pa, K1, N0, N0 / 2);
  pool_x<<<K1, 256, 0, stream>>>(x0, perm1, vals, xp);

  // ---- GCN 1 ----
  hipMemsetAsync(deg, 0, K1 * 4, stream);
  transpose_deg<1><<<dim3(K1 / 64, K1 / 64), 256, 0, stream>>>(Pa, K1, At, deg);
  xw_gemm<<<dim3(K1 / 64, CH / 64), 256, 0, stream>>>(xp, w1, Gt, K1, deg);
  hipMemsetAsync(Cacc, 0, (size_t)K1 * CH * 4, stream);
  mfma_nt<<<dim3(K1 / 128, CH / 128, 8), 256, 0, stream>>>(At, Gt, Cacc, CH, K1, K1 / 8);
  agg_epilogue<<<K1 / 4, 256, 0, stream>>>(Cacc, deg, b1, x1, p2, sc);

  // ---- pool 2 ----
  topk_sort<<<1, 1024, 0, stream>>>(sc, K1, K2, perm2, vals);

  // ---- augment L2 ----
  rowgather_cvt<<<dim3(K1 / 1024, K2), 256, 0, stream>>>(Pa, perm2, K1, Arow);
  rowgather_bf16<<<dim3(K1 / 2048, K2), 256, 0, stream>>>(At, perm2, K1, Brow);
  hipMemsetAsync(Pb, 0, (size_t)K2 * K2 * 4, stream);
  mfma_nt<<<dim3(K2 / 128, K2 / 128, 4), 256, 0, stream>>>(Arow, Brow, Pb, K2, K1, K1 / 4);
  pool_x<<<K2, 256, 0, stream>>>(x1, perm2, vals, xp);

  // ---- GCN 2 ----
  hipMemsetAsync(deg, 0, K2 * 4, stream);
  transpose_deg<1><<<dim3(K2 / 64, K2 / 64), 256, 0, stream>>>(Pb, K2, At, deg);
  xw_gemm<<<dim3(K2 / 64, CH / 64), 256, 0, stream>>>(xp, w2, Gt, K2, deg);
  hipMemsetAsync(Cacc, 0, (size_t)K2 * CH * 4, stream);
  mfma_nt<<<dim3(K2 / 128, CH / 128, 16), 256, 0, stream>>>(At, Gt, Cacc, CH, K2, K2 / 16);
  agg_epilogue<<<K2 / 4, 256, 0, stream>>>(Cacc, deg, b2, x2, nullptr, nullptr);

  // ---- readout ----
  hipMemsetAsync(macc, 0, 256 * 4, stream);
  mean_partial<<<K2 / 16, 256, 0, stream>>>(x2, macc);
  finalize2<<<1, 256, 0, stream>>>(macc, K2, wc, bc, out);
}